// Round 3
// baseline (197.616 us; speedup 1.0000x reference)
//
#include <hip/hip_runtime.h>
#include <hip/hip_bf16.h>

// StackedAdapter: out[b] = x[b] + W2[g]^T·relu(W1[g]^T·LN(x[b]) + B1[g]) + B2[g]
// B=32, S=512, D=1024, F=2048. 16384 tokens, 4096 per group, 4 groups.

#define S_DIM 512
#define D_DIM 1024
#define F_DIM 2048
#define MPG   4096

typedef __attribute__((ext_vector_type(8))) short  short8;   // 8 bf16
typedef __attribute__((ext_vector_type(4))) float  f32x4;

__device__ __forceinline__ void gll16(const void* g, void* l) {
  __builtin_amdgcn_global_load_lds((__attribute__((address_space(1))) void*)g,
                                   (__attribute__((address_space(3))) void*)l,
                                   16, 0, 0);
}
#define VMC2()  asm volatile("s_waitcnt vmcnt(2)" ::: "memory")
#define VMC4()  asm volatile("s_waitcnt vmcnt(4)" ::: "memory")
#define SB()    __builtin_amdgcn_sched_barrier(0)
#define BAR()   __builtin_amdgcn_s_barrier()

// ---------------------------------------------------------------------------
// Kernel 1: cast f32 weights to bf16 with transpose: [g][K][N] -> [g][N][K]
// ---------------------------------------------------------------------------
__global__ __launch_bounds__(256) void transpose_cast_kernel(
    const float* __restrict__ W1, const float* __restrict__ W2,
    __hip_bfloat16* __restrict__ W1t, __hip_bfloat16* __restrict__ W2t)
{
  __shared__ float tl[32][33];
  const int bid = blockIdx.x;
  const float* src; __hip_bfloat16* dst;
  int R, C, tr, tc;
  if (bid < 8192) {                 // W1: [4][1024][2048] -> [4][2048][1024]
    const int g = bid >> 11, t = bid & 2047;
    R = 1024; C = 2048; tr = t >> 6; tc = t & 63;
    src = W1 + (size_t)g * R * C;
    dst = W1t + (size_t)g * R * C;
  } else {                          // W2: [4][2048][1024] -> [4][1024][2048]
    const int b2 = bid - 8192;
    const int g = b2 >> 11, t = b2 & 2047;
    R = 2048; C = 1024; tr = t >> 5; tc = t & 31;
    src = W2 + (size_t)g * R * C;
    dst = W2t + (size_t)g * R * C;
  }
  const int tx = threadIdx.x & 31, ty = threadIdx.x >> 5;
  const int r0 = tr * 32, c0 = tc * 32;
#pragma unroll
  for (int i = 0; i < 4; ++i)
    tl[ty + 8 * i][tx] = src[(size_t)(r0 + ty + 8 * i) * C + (c0 + tx)];
  __syncthreads();
#pragma unroll
  for (int i = 0; i < 4; ++i)
    dst[(size_t)(c0 + ty + 8 * i) * R + (r0 + tx)] = __float2bfloat16(tl[tx][ty + 8 * i]);
}

// ---------------------------------------------------------------------------
// Kernel 2: LayerNorm + gather into group-major order, cast to bf16.
// ---------------------------------------------------------------------------
__global__ __launch_bounds__(256) void ln_gather_kernel(
    const float* __restrict__ x, const int* __restrict__ idx,
    const float* __restrict__ G, const float* __restrict__ Bn,
    __hip_bfloat16* __restrict__ Xn)
{
  const int wid  = (blockIdx.x * 256 + threadIdx.x) >> 6;
  const int lane = threadIdx.x & 63;
  const int g = wid >> 12;
  const int r = wid & 4095;
  const int j = r >> 9;
  const int tok = r & 511;
  const int b = idx[g * 8 + j];

  const float* src = x + ((size_t)b * S_DIM + tok) * D_DIM + lane * 16;
  float4 vq[4];
#pragma unroll
  for (int i = 0; i < 4; ++i) vq[i] = ((const float4*)src)[i];
  const float* va = (const float*)vq;

  float s = 0.f, s2 = 0.f;
#pragma unroll
  for (int i = 0; i < 16; ++i) { s += va[i]; s2 += va[i] * va[i]; }
#pragma unroll
  for (int o = 32; o > 0; o >>= 1) { s += __shfl_xor(s, o); s2 += __shfl_xor(s2, o); }

  const float mu  = s * (1.0f / 1024.0f);
  float var = fmaxf(s2 * (1.0f / 1024.0f) - mu * mu, 0.0f) * (1024.0f / 1023.0f);
  const float rs  = 1.0f / (sqrtf(var) + 1e-6f);

  float4 gq[4], bq[4];
  const float* gp = G  + (size_t)g * D_DIM + lane * 16;
  const float* bp = Bn + (size_t)g * D_DIM + lane * 16;
#pragma unroll
  for (int i = 0; i < 4; ++i) { gq[i] = ((const float4*)gp)[i]; bq[i] = ((const float4*)bp)[i]; }
  const float* ga = (const float*)gq;
  const float* be = (const float*)bq;

  __align__(16) __hip_bfloat16 ob[16];
#pragma unroll
  for (int i = 0; i < 16; ++i)
    ob[i] = __float2bfloat16(ga[i] * (va[i] - mu) * rs + be[i]);

  __hip_bfloat16* dst = Xn + ((size_t)g * MPG + r) * D_DIM + lane * 16;
  ((uint4*)dst)[0] = *(const uint4*)&ob[0];
  ((uint4*)dst)[1] = *(const uint4*)&ob[8];
}

// ---------------------------------------------------------------------------
// Kernels 3/4: bf16 MFMA GEMM, 256x256 tile, BK=64, 8 waves (2Mx4N).
// 4 phases per K-tile; each phase issues the NEXT phase's ds_reads BEFORE the
// barrier (drain absorbed by barrier wait + previous MFMA), stages one 16KB
// plane of tile t+1, then runs 16 MFMA on fragments read last phase.
// Counted vmcnt(2) before the barriers of phases 1 and 3 only (planes land
// 3 phases after issue). Register frags ping-pong (frA0/frA1, frB0/frB1).
//
// LDS buffer (64KB x2): planes {A kh0 @0, B kh0 @16K, A kh1 @32K, B kh1 @48K}.
// Plane = [128 lines][128B]; line holds a row-pair; 16B-slot permutation
//   phys_slot(r,s) = ((r&1)*4+s) ^ ((r>>1)&7)
// applied on the read side AND (inverse) on the per-lane global source, LDS
// dest linear (rule 21). Conflict-free (R2: SQ_LDS_BANK_CONFLICT = 0).
// ---------------------------------------------------------------------------
template <bool SECOND>
__global__ __launch_bounds__(512, 2) void gemm_kernel(
    const __hip_bfloat16* __restrict__ A,
    const __hip_bfloat16* __restrict__ Bw,
    const float* __restrict__ bias,
    const float* __restrict__ xres,
    const int* __restrict__ idx,
    __hip_bfloat16* __restrict__ obf,
    float* __restrict__ of32,
    const int N, const int K, const int NT)
{
  extern __shared__ char lds[];     // 131072 bytes
  const int ntile = N >> 8;
  const int nwg = gridDim.x;
  const int bid0 = blockIdx.x;
  const int bid = (bid0 & 7) * (nwg >> 3) + (bid0 >> 3);   // XCD-contiguous
  const int mt = bid / ntile, nt = bid % ntile;
  const int g  = mt >> 4;
  const int tid = threadIdx.x;
  const int w = tid >> 6, lane = tid & 63;
  const int wm = w >> 2, wn = w & 3;

  const __hip_bfloat16* Ab = A + (size_t)mt * 256 * K;
  const __hip_bfloat16* Bb = Bw + ((size_t)g * N + (size_t)nt * 256) * K;

  // staging decode: inverse slot permutation on the global source address
  const int sp   = (lane & 7) ^ ((lane >> 3) & 7);
  const int srow = 2 * (lane >> 3) + (sp >> 2);
  const int skof = (sp & 3) * 8;
  const __hip_bfloat16* Ag0 = Ab + (size_t)(w * 32 + srow) * K + skof;
  const __hip_bfloat16* Ag1 = Ag0 + (size_t)16 * K;
  const __hip_bfloat16* Bg0 = Bb + (size_t)(w * 32 + srow) * K + skof;
  const __hip_bfloat16* Bg1 = Bg0 + (size_t)16 * K;

  // read-side lane constant (physical slot)
  const int l15 = lane & 15, sl = lane >> 4;
  const int slot_phys = (((l15 & 1) << 2) + sl) ^ ((l15 >> 1) & 7);
  const int lane_c = ((l15 >> 1) << 7) + (slot_phys << 4);

  f32x4 acc[8][4] = {};
  short8 frA0[4], frA1[4], frB0[4], frB1[4];

#define STAGE(BUFX, MAT, KH, TN) {                                          \
    const int koff = (TN) * 64 + (KH) * 32;                                 \
    char* d = lds + (BUFX) + ((KH) * 2 + (MAT)) * 16384 + w * 2048;         \
    if (MAT) { gll16(Bg0 + koff, d); gll16(Bg1 + koff, d + 1024); }         \
    else     { gll16(Ag0 + koff, d); gll16(Ag1 + koff, d + 1024); } }

#define RDA(DST, BUFX, KH, MH) {                                            \
    const char* base_ = lds + (BUFX) + (KH) * 32768 + wm * 8192 +           \
                        (MH) * 4096 + lane_c;                               \
    _Pragma("unroll") for (int mm = 0; mm < 4; ++mm)                        \
      DST[mm] = *(const short8*)(base_ + mm * 1024); }

#define RDB(DST, BUFX, KH) {                                                \
    const char* base_ = lds + (BUFX) + 16384 + (KH) * 32768 + wn * 4096 +   \
                        lane_c;                                             \
    _Pragma("unroll") for (int n = 0; n < 4; ++n)                           \
      DST[n] = *(const short8*)(base_ + n * 1024); }

#define MF(MH, FA, FB) {                                                    \
    __builtin_amdgcn_s_setprio(1);                                          \
    _Pragma("unroll") for (int mm = 0; mm < 4; ++mm)                        \
      _Pragma("unroll") for (int n = 0; n < 4; ++n)                         \
        acc[(MH) * 4 + mm][n] = __builtin_amdgcn_mfma_f32_16x16x32_bf16(    \
            FA[mm], FB[n], acc[(MH) * 4 + mm][n], 0, 0, 0);                 \
    __builtin_amdgcn_s_setprio(0); }

  // prologue: stage tile 0, wait first two planes, pre-read phase-0 frags
  STAGE(0, 0, 0, 0); STAGE(0, 1, 0, 0); STAGE(0, 0, 1, 0); STAGE(0, 1, 1, 0);
  VMC4();
  BAR();
  RDA(frA0, 0, 0, 0);
  RDB(frB0, 0, 0);

  for (int t = 0; t < NT; ++t) {
    const int bufb = (t & 1) << 16;
    const int bufx = bufb ^ 65536;
    const int tn = (t + 1 == NT) ? 0 : t + 1;   // wrap: dummy restage
    // ph0: compute kh0/MH0 ; read kh0/MH1 ; stage A' kh0
    SB(); BAR(); SB();
    RDA(frA1, bufb, 0, 1);
    STAGE(bufx, 0, 0, tn);
    SB();
    MF(0, frA0, frB0);
    // ph1: compute kh0/MH1 ; read kh1/MH0 + B kh1 ; stage B' kh0
    SB(); VMC2(); BAR(); SB();
    RDA(frA0, bufb, 1, 0);
    RDB(frB1, bufb, 1);
    STAGE(bufx, 1, 0, tn);
    SB();
    MF(1, frA1, frB0);
    // ph2: compute kh1/MH0 ; read kh1/MH1 ; stage A' kh1
    SB(); BAR(); SB();
    RDA(frA1, bufb, 1, 1);
    STAGE(bufx, 0, 1, tn);
    SB();
    MF(0, frA0, frB1);
    // ph3: compute kh1/MH1 ; read NEXT tile kh0/MH0 + B' kh0 ; stage B' kh1
    SB(); VMC2(); BAR(); SB();
    RDA(frA0, bufx, 0, 0);
    RDB(frB0, bufx, 0);
    STAGE(bufx, 1, 1, tn);
    SB();
    MF(1, frA1, frB1);
  }
#undef STAGE
#undef RDA
#undef RDB
#undef MF

  // C/D layout: col = lane&15, row = (lane>>4)*4 + i   [m89/m91]
  const int cc  = lane & 15;
  const int cr4 = (lane >> 4) * 4;

  float bv[4];
#pragma unroll
  for (int n = 0; n < 4; ++n)
    bv[n] = bias[(size_t)g * N + nt * 256 + wn * 64 + n * 16 + cc];

  if constexpr (!SECOND) {
#pragma unroll
    for (int m = 0; m < 8; ++m) {
      const int grow0 = mt * 256 + wm * 128 + m * 16 + cr4;
#pragma unroll
      for (int n = 0; n < 4; ++n) {
        const int gcol = nt * 256 + wn * 64 + n * 16 + cc;
#pragma unroll
        for (int i = 0; i < 4; ++i) {
          const float v = fmaxf(acc[m][n][i] + bv[n], 0.0f);
          obf[(size_t)(grow0 + i) * N + gcol] = __float2bfloat16(v);
        }
      }
    }
  } else {
    const int rbase = (mt & 15) * 256;
    const int b = idx[g * 8 + (rbase >> 9)];
    const size_t ob = (size_t)b * S_DIM * D_DIM;
#pragma unroll
    for (int m = 0; m < 8; ++m) {
      const int rloc = rbase + wm * 128 + m * 16 + cr4;
#pragma unroll
      for (int n = 0; n < 4; ++n) {
        const int gcol = nt * 256 + wn * 64 + n * 16 + cc;
#pragma unroll
        for (int i = 0; i < 4; ++i) {
          const int tok = (rloc + i) & 511;
          const size_t off = ob + (size_t)tok * D_DIM + gcol;
          of32[off] = acc[m][n][i] + bv[n] + xres[off];
        }
      }
    }
  }
}

// ---------------------------------------------------------------------------
extern "C" void kernel_launch(void* const* d_in, const int* in_sizes, int n_in,
                              void* d_out, int out_size, void* d_ws, size_t ws_size,
                              hipStream_t stream) {
  const float* x  = (const float*)d_in[0];
  const int*   idx = (const int*)d_in[1];
  const float* W1 = (const float*)d_in[2];
  const float* B1 = (const float*)d_in[3];
  const float* W2 = (const float*)d_in[4];
  const float* B2 = (const float*)d_in[5];
  const float* G  = (const float*)d_in[6];
  const float* Bn = (const float*)d_in[7];
  float* out = (float*)d_out;

  char* ws = (char*)d_ws;
  __hip_bfloat16* Xn  = (__hip_bfloat16*)(ws);                    // 32 MiB
  __hip_bfloat16* W1t = (__hip_bfloat16*)(ws + 33554432);         // 16 MiB
  __hip_bfloat16* W2t = (__hip_bfloat16*)(ws + 50331648);         // 16 MiB
  __hip_bfloat16* H1  = (__hip_bfloat16*)(ws + 67108864);         // 64 MiB

  (void)hipFuncSetAttribute((const void*)gemm_kernel<false>,
                            hipFuncAttributeMaxDynamicSharedMemorySize, 131072);
  (void)hipFuncSetAttribute((const void*)gemm_kernel<true>,
                            hipFuncAttributeMaxDynamicSharedMemorySize, 131072);

  transpose_cast_kernel<<<dim3(16384), dim3(256), 0, stream>>>(W1, W2, W1t, W2t);
  ln_gather_kernel<<<dim3(4096), dim3(256), 0, stream>>>(x, idx, G, Bn, Xn);
  gemm_kernel<false><<<dim3(512), dim3(512), 131072, stream>>>(
      Xn, W1t, B1, nullptr, nullptr, H1, nullptr, F_DIM, D_DIM, 16);
  gemm_kernel<true><<<dim3(256), dim3(512), 131072, stream>>>(
      H1, W2t, B2, x, idx, nullptr, out, D_DIM, F_DIM, 32);
}

// Round 4
// 189.080 us; speedup vs baseline: 1.0451x; 1.0451x over previous
//
#include <hip/hip_runtime.h>
#include <hip/hip_bf16.h>

// StackedAdapter: out[b] = x[b] + W2[g]^T·relu(W1[g]^T·LN(x[b]) + B1[g]) + B2[g]
// B=32, S=512, D=1024, F=2048. 16384 tokens, 4096 per group, 4 groups.

#define S_DIM 512
#define D_DIM 1024
#define F_DIM 2048
#define MPG   4096

typedef __attribute__((ext_vector_type(8))) short  short8;   // 8 bf16
typedef __attribute__((ext_vector_type(4))) float  f32x4;

__device__ __forceinline__ void gll16(const void* g, void* l) {
  __builtin_amdgcn_global_load_lds((__attribute__((address_space(1))) void*)g,
                                   (__attribute__((address_space(3))) void*)l,
                                   16, 0, 0);
}
#define VMC4()  asm volatile("s_waitcnt vmcnt(4)" ::: "memory")
#define LGKM0() asm volatile("s_waitcnt lgkmcnt(0)" ::: "memory")
#define SB()    __builtin_amdgcn_sched_barrier(0)
#define BAR()   __builtin_amdgcn_s_barrier()

// ---------------------------------------------------------------------------
// Kernel 1: cast f32 weights to bf16 with transpose: [g][K][N] -> [g][N][K]
// ---------------------------------------------------------------------------
__global__ __launch_bounds__(256) void transpose_cast_kernel(
    const float* __restrict__ W1, const float* __restrict__ W2,
    __hip_bfloat16* __restrict__ W1t, __hip_bfloat16* __restrict__ W2t)
{
  __shared__ float tl[32][33];
  const int bid = blockIdx.x;
  const float* src; __hip_bfloat16* dst;
  int R, C, tr, tc;
  if (bid < 8192) {                 // W1: [4][1024][2048] -> [4][2048][1024]
    const int g = bid >> 11, t = bid & 2047;
    R = 1024; C = 2048; tr = t >> 6; tc = t & 63;
    src = W1 + (size_t)g * R * C;
    dst = W1t + (size_t)g * R * C;
  } else {                          // W2: [4][2048][1024] -> [4][1024][2048]
    const int b2 = bid - 8192;
    const int g = b2 >> 11, t = b2 & 2047;
    R = 2048; C = 1024; tr = t >> 5; tc = t & 31;
    src = W2 + (size_t)g * R * C;
    dst = W2t + (size_t)g * R * C;
  }
  const int tx = threadIdx.x & 31, ty = threadIdx.x >> 5;
  const int r0 = tr * 32, c0 = tc * 32;
#pragma unroll
  for (int i = 0; i < 4; ++i)
    tl[ty + 8 * i][tx] = src[(size_t)(r0 + ty + 8 * i) * C + (c0 + tx)];
  __syncthreads();
#pragma unroll
  for (int i = 0; i < 4; ++i)
    dst[(size_t)(c0 + ty + 8 * i) * R + (r0 + tx)] = __float2bfloat16(tl[tx][ty + 8 * i]);
}

// ---------------------------------------------------------------------------
// Kernel 2: LayerNorm + gather into group-major order, cast to bf16.
// ---------------------------------------------------------------------------
__global__ __launch_bounds__(256) void ln_gather_kernel(
    const float* __restrict__ x, const int* __restrict__ idx,
    const float* __restrict__ G, const float* __restrict__ Bn,
    __hip_bfloat16* __restrict__ Xn)
{
  const int wid  = (blockIdx.x * 256 + threadIdx.x) >> 6;
  const int lane = threadIdx.x & 63;
  const int g = wid >> 12;
  const int r = wid & 4095;
  const int j = r >> 9;
  const int tok = r & 511;
  const int b = idx[g * 8 + j];

  const float* src = x + ((size_t)b * S_DIM + tok) * D_DIM + lane * 16;
  float4 vq[4];
#pragma unroll
  for (int i = 0; i < 4; ++i) vq[i] = ((const float4*)src)[i];
  const float* va = (const float*)vq;

  float s = 0.f, s2 = 0.f;
#pragma unroll
  for (int i = 0; i < 16; ++i) { s += va[i]; s2 += va[i] * va[i]; }
#pragma unroll
  for (int o = 32; o > 0; o >>= 1) { s += __shfl_xor(s, o); s2 += __shfl_xor(s2, o); }

  const float mu  = s * (1.0f / 1024.0f);
  float var = fmaxf(s2 * (1.0f / 1024.0f) - mu * mu, 0.0f) * (1024.0f / 1023.0f);
  const float rs  = 1.0f / (sqrtf(var) + 1e-6f);

  float4 gq[4], bq[4];
  const float* gp = G  + (size_t)g * D_DIM + lane * 16;
  const float* bp = Bn + (size_t)g * D_DIM + lane * 16;
#pragma unroll
  for (int i = 0; i < 4; ++i) { gq[i] = ((const float4*)gp)[i]; bq[i] = ((const float4*)bp)[i]; }
  const float* ga = (const float*)gq;
  const float* be = (const float*)bq;

  __align__(16) __hip_bfloat16 ob[16];
#pragma unroll
  for (int i = 0; i < 16; ++i)
    ob[i] = __float2bfloat16(ga[i] * (va[i] - mu) * rs + be[i]);

  __hip_bfloat16* dst = Xn + ((size_t)g * MPG + r) * D_DIM + lane * 16;
  ((uint4*)dst)[0] = *(const uint4*)&ob[0];
  ((uint4*)dst)[1] = *(const uint4*)&ob[8];
}

// ---------------------------------------------------------------------------
// Kernels 3/4: bf16 MFMA GEMM, 256x256 tile, BK=64, 8 waves (2Mx4N).
// m201 per-phase rhythm: {ds_read subtile; stage 1 plane; [vmcnt(4)];
//   BAR; lgkmcnt(0); setprio(1); 16 MFMA; setprio(0); BAR}.
// 4 phases per K-tile (quadrant = K-half x M-half). Counted vmcnt(4) at
// phases 2 and 4 only — positionally derived: per-wave gll queue is exactly
// 8 deep at each check; vmcnt(4) retires the 2 planes read next, each issued
// >=2 phases (~1000+ cyc) earlier => no stall. Never vmcnt(0) in loop.
//
// LDS 2x64KB buffers, 4 planes {A kh0, B kh0, A kh1, B kh1} @ 16KB each.
// Plane = [128 lines][128B], line = row-pair; 16B-slot permutation
//   phys_slot(r,s) = ((r&1)*4+s) ^ ((r>>1)&7)
// on read side + inverse on per-lane global source; LDS dest linear
// (rule 21). Conflict-free (R2/R3: SQ_LDS_BANK_CONFLICT = 0).
// ---------------------------------------------------------------------------
template <bool SECOND>
__global__ __launch_bounds__(512, 2) void gemm_kernel(
    const __hip_bfloat16* __restrict__ A,
    const __hip_bfloat16* __restrict__ Bw,
    const float* __restrict__ bias,
    const float* __restrict__ xres,
    const int* __restrict__ idx,
    __hip_bfloat16* __restrict__ obf,
    float* __restrict__ of32,
    const int N, const int K, const int NT)
{
  extern __shared__ char lds[];     // 131072 bytes
  const int ntile = N >> 8;
  const int nwg = gridDim.x;
  const int bid0 = blockIdx.x;
  const int bid = (bid0 & 7) * (nwg >> 3) + (bid0 >> 3);   // XCD-contiguous
  const int mt = bid / ntile, nt = bid % ntile;
  const int g  = mt >> 4;
  const int tid = threadIdx.x;
  const int w = tid >> 6, lane = tid & 63;
  const int wm = w >> 2, wn = w & 3;

  const __hip_bfloat16* Ab = A + (size_t)mt * 256 * K;
  const __hip_bfloat16* Bb = Bw + ((size_t)g * N + (size_t)nt * 256) * K;

  // staging decode: inverse slot permutation on the global source address
  const int sp   = (lane & 7) ^ ((lane >> 3) & 7);
  const int srow = 2 * (lane >> 3) + (sp >> 2);
  const int skof = (sp & 3) * 8;
  const __hip_bfloat16* Ag0 = Ab + (size_t)(w * 32 + srow) * K + skof;
  const __hip_bfloat16* Ag1 = Ag0 + (size_t)16 * K;
  const __hip_bfloat16* Bg0 = Bb + (size_t)(w * 32 + srow) * K + skof;
  const __hip_bfloat16* Bg1 = Bg0 + (size_t)16 * K;

  // read-side lane constant (physical slot)
  const int l15 = lane & 15, sl = lane >> 4;
  const int slot_phys = (((l15 & 1) << 2) + sl) ^ ((l15 >> 1) & 7);
  const int lane_c = ((l15 >> 1) << 7) + (slot_phys << 4);

  f32x4 acc[8][4] = {};
  short8 frA[4], frB[4];

#define STAGE(BUFX, MAT, KH, TN) {                                          \
    const int koff = (TN) * 64 + (KH) * 32;                                 \
    char* d = lds + (BUFX) + ((KH) * 2 + (MAT)) * 16384 + w * 2048;         \
    if (MAT) { gll16(Bg0 + koff, d); gll16(Bg1 + koff, d + 1024); }         \
    else     { gll16(Ag0 + koff, d); gll16(Ag1 + koff, d + 1024); } }

#define RDA(BUFX, KH, MH) {                                                 \
    const char* base_ = lds + (BUFX) + (KH) * 32768 + wm * 8192 +           \
                        (MH) * 4096 + lane_c;                               \
    _Pragma("unroll") for (int mm = 0; mm < 4; ++mm)                        \
      frA[mm] = *(const short8*)(base_ + mm * 1024); }

#define RDB(BUFX, KH) {                                                     \
    const char* base_ = lds + (BUFX) + 16384 + (KH) * 32768 + wn * 4096 +   \
                        lane_c;                                             \
    _Pragma("unroll") for (int n = 0; n < 4; ++n)                           \
      frB[n] = *(const short8*)(base_ + n * 1024); }

#define MF(MH) {                                                            \
    __builtin_amdgcn_s_setprio(1);                                          \
    _Pragma("unroll") for (int mm = 0; mm < 4; ++mm)                        \
      _Pragma("unroll") for (int n = 0; n < 4; ++n)                         \
        acc[(MH) * 4 + mm][n] = __builtin_amdgcn_mfma_f32_16x16x32_bf16(    \
            frA[mm], frB[n], acc[(MH) * 4 + mm][n], 0, 0, 0);               \
    __builtin_amdgcn_s_setprio(0); }

  // prologue: stage tile 0 (8 gll ops), guarantee first 2 planes, publish
  STAGE(0, 0, 0, 0); STAGE(0, 1, 0, 0); STAGE(0, 0, 1, 0); STAGE(0, 1, 1, 0);
  VMC4();            // A kh0, B kh0 landed (S3,S4 still in flight)
  BAR();

  for (int t = 0; t < NT; ++t) {
    const int bufb = (t & 1) << 16;
    const int bufx = bufb ^ 65536;
    const int tn = (t + 1 == NT) ? 0 : t + 1;   // wrap: dummy restage
    // ph1: read kh0/MH0 + B kh0 ; stage A'kh0 ; MFMA(kh0,MH0)
    RDA(bufb, 0, 0); RDB(bufb, 0);
    STAGE(bufx, 0, 0, tn);
    SB(); BAR(); LGKM0(); SB();
    MF(0);
    BAR();
    // ph2: read kh0/MH1 ; stage B'kh0 ; vmcnt(4) -> S3,S4(t) landed ; MFMA
    RDA(bufb, 0, 1);
    STAGE(bufx, 1, 0, tn);
    VMC4();
    SB(); BAR(); LGKM0(); SB();
    MF(1);
    BAR();
    // ph3: read kh1/MH0 + B kh1 ; stage A'kh1 ; MFMA(kh1,MH0)
    RDA(bufb, 1, 0); RDB(bufb, 1);
    STAGE(bufx, 0, 1, tn);
    SB(); BAR(); LGKM0(); SB();
    MF(0);
    BAR();
    // ph4: read kh1/MH1 ; stage B'kh1 ; vmcnt(4) -> S1',S2' landed ; MFMA
    RDA(bufb, 1, 1);
    STAGE(bufx, 1, 1, tn);
    VMC4();
    SB(); BAR(); LGKM0(); SB();
    MF(1);
    BAR();
  }
#undef STAGE
#undef RDA
#undef RDB
#undef MF

  // C/D layout: col = lane&15, row = (lane>>4)*4 + i   [m89/m91]
  const int cc  = lane & 15;
  const int cr4 = (lane >> 4) * 4;

  float bv[4];
#pragma unroll
  for (int n = 0; n < 4; ++n)
    bv[n] = bias[(size_t)g * N + nt * 256 + wn * 64 + n * 16 + cc];

  if constexpr (!SECOND) {
#pragma unroll
    for (int m = 0; m < 8; ++m) {
      const int grow0 = mt * 256 + wm * 128 + m * 16 + cr4;
#pragma unroll
      for (int n = 0; n < 4; ++n) {
        const int gcol = nt * 256 + wn * 64 + n * 16 + cc;
#pragma unroll
        for (int i = 0; i < 4; ++i) {
          const float v = fmaxf(acc[m][n][i] + bv[n], 0.0f);
          obf[(size_t)(grow0 + i) * N + gcol] = __float2bfloat16(v);
        }
      }
    }
  } else {
    const int rbase = (mt & 15) * 256;
    const int b = idx[g * 8 + (rbase >> 9)];
    const size_t ob = (size_t)b * S_DIM * D_DIM;
#pragma unroll
    for (int m = 0; m < 8; ++m) {
      const int rloc = rbase + wm * 128 + m * 16 + cr4;
#pragma unroll
      for (int n = 0; n < 4; ++n) {
        const int gcol = nt * 256 + wn * 64 + n * 16 + cc;
#pragma unroll
        for (int i = 0; i < 4; ++i) {
          const int tok = (rloc + i) & 511;
          const size_t off = ob + (size_t)tok * D_DIM + gcol;
          of32[off] = acc[m][n][i] + bv[n] + xres[off];
        }
      }
    }
  }
}

// ---------------------------------------------------------------------------
extern "C" void kernel_launch(void* const* d_in, const int* in_sizes, int n_in,
                              void* d_out, int out_size, void* d_ws, size_t ws_size,
                              hipStream_t stream) {
  const float* x  = (const float*)d_in[0];
  const int*   idx = (const int*)d_in[1];
  const float* W1 = (const float*)d_in[2];
  const float* B1 = (const float*)d_in[3];
  const float* W2 = (const float*)d_in[4];
  const float* B2 = (const float*)d_in[5];
  const float* G  = (const float*)d_in[6];
  const float* Bn = (const float*)d_in[7];
  float* out = (float*)d_out;

  char* ws = (char*)d_ws;
  __hip_bfloat16* Xn  = (__hip_bfloat16*)(ws);                    // 32 MiB
  __hip_bfloat16* W1t = (__hip_bfloat16*)(ws + 33554432);         // 16 MiB
  __hip_bfloat16* W2t = (__hip_bfloat16*)(ws + 50331648);         // 16 MiB
  __hip_bfloat16* H1  = (__hip_bfloat16*)(ws + 67108864);         // 64 MiB

  (void)hipFuncSetAttribute((const void*)gemm_kernel<false>,
                            hipFuncAttributeMaxDynamicSharedMemorySize, 131072);
  (void)hipFuncSetAttribute((const void*)gemm_kernel<true>,
                            hipFuncAttributeMaxDynamicSharedMemorySize, 131072);

  transpose_cast_kernel<<<dim3(16384), dim3(256), 0, stream>>>(W1, W2, W1t, W2t);
  ln_gather_kernel<<<dim3(4096), dim3(256), 0, stream>>>(x, idx, G, Bn, Xn);
  gemm_kernel<false><<<dim3(512), dim3(512), 131072, stream>>>(
      Xn, W1t, B1, nullptr, nullptr, H1, nullptr, F_DIM, D_DIM, 16);
  gemm_kernel<true><<<dim3(256), dim3(512), 131072, stream>>>(
      H1, W2t, B2, x, idx, nullptr, out, D_DIM, F_DIM, 32);
}

// Round 5
// 183.856 us; speedup vs baseline: 1.0748x; 1.0284x over previous
//
#include <hip/hip_runtime.h>
#include <hip/hip_bf16.h>

// StackedAdapter: out[b] = x[b] + W2[g]^T·relu(W1[g]^T·LN(x[b]) + B1[g]) + B2[g]
// B=32, S=512, D=1024, F=2048. 16384 tokens, 4096 per group, 4 groups.

#define S_DIM 512
#define D_DIM 1024
#define F_DIM 2048
#define MPG   4096

typedef __attribute__((ext_vector_type(8))) short  short8;   // 8 bf16
typedef __attribute__((ext_vector_type(4))) float  f32x4;

__device__ __forceinline__ void gll16(const void* g, void* l) {
  __builtin_amdgcn_global_load_lds((__attribute__((address_space(1))) void*)g,
                                   (__attribute__((address_space(3))) void*)l,
                                   16, 0, 0);
}
#define VMC4()  asm volatile("s_waitcnt vmcnt(4)" ::: "memory")
#define BAR()   __builtin_amdgcn_s_barrier()

// ---------------------------------------------------------------------------
// Kernel 1: cast f32 weights to bf16 with transpose: [g][K][N] -> [g][N][K]
// ---------------------------------------------------------------------------
__global__ __launch_bounds__(256) void transpose_cast_kernel(
    const float* __restrict__ W1, const float* __restrict__ W2,
    __hip_bfloat16* __restrict__ W1t, __hip_bfloat16* __restrict__ W2t)
{
  __shared__ float tl[32][33];
  const int bid = blockIdx.x;
  const float* src; __hip_bfloat16* dst;
  int R, C, tr, tc;
  if (bid < 8192) {                 // W1: [4][1024][2048] -> [4][2048][1024]
    const int g = bid >> 11, t = bid & 2047;
    R = 1024; C = 2048; tr = t >> 6; tc = t & 63;
    src = W1 + (size_t)g * R * C;
    dst = W1t + (size_t)g * R * C;
  } else {                          // W2: [4][2048][1024] -> [4][1024][2048]
    const int b2 = bid - 8192;
    const int g = b2 >> 11, t = b2 & 2047;
    R = 2048; C = 1024; tr = t >> 5; tc = t & 31;
    src = W2 + (size_t)g * R * C;
    dst = W2t + (size_t)g * R * C;
  }
  const int tx = threadIdx.x & 31, ty = threadIdx.x >> 5;
  const int r0 = tr * 32, c0 = tc * 32;
#pragma unroll
  for (int i = 0; i < 4; ++i)
    tl[ty + 8 * i][tx] = src[(size_t)(r0 + ty + 8 * i) * C + (c0 + tx)];
  __syncthreads();
#pragma unroll
  for (int i = 0; i < 4; ++i)
    dst[(size_t)(c0 + ty + 8 * i) * R + (r0 + tx)] = __float2bfloat16(tl[tx][ty + 8 * i]);
}

// ---------------------------------------------------------------------------
// Kernel 2: LayerNorm + gather into group-major order, cast to bf16.
// ---------------------------------------------------------------------------
__global__ __launch_bounds__(256) void ln_gather_kernel(
    const float* __restrict__ x, const int* __restrict__ idx,
    const float* __restrict__ G, const float* __restrict__ Bn,
    __hip_bfloat16* __restrict__ Xn)
{
  const int wid  = (blockIdx.x * 256 + threadIdx.x) >> 6;
  const int lane = threadIdx.x & 63;
  const int g = wid >> 12;
  const int r = wid & 4095;
  const int j = r >> 9;
  const int tok = r & 511;
  const int b = idx[g * 8 + j];

  const float* src = x + ((size_t)b * S_DIM + tok) * D_DIM + lane * 16;
  float4 vq[4];
#pragma unroll
  for (int i = 0; i < 4; ++i) vq[i] = ((const float4*)src)[i];
  const float* va = (const float*)vq;

  float s = 0.f, s2 = 0.f;
#pragma unroll
  for (int i = 0; i < 16; ++i) { s += va[i]; s2 += va[i] * va[i]; }
#pragma unroll
  for (int o = 32; o > 0; o >>= 1) { s += __shfl_xor(s, o); s2 += __shfl_xor(s2, o); }

  const float mu  = s * (1.0f / 1024.0f);
  float var = fmaxf(s2 * (1.0f / 1024.0f) - mu * mu, 0.0f) * (1024.0f / 1023.0f);
  const float rs  = 1.0f / (sqrtf(var) + 1e-6f);

  float4 gq[4], bq[4];
  const float* gp = G  + (size_t)g * D_DIM + lane * 16;
  const float* bp = Bn + (size_t)g * D_DIM + lane * 16;
#pragma unroll
  for (int i = 0; i < 4; ++i) { gq[i] = ((const float4*)gp)[i]; bq[i] = ((const float4*)bp)[i]; }
  const float* ga = (const float*)gq;
  const float* be = (const float*)bq;

  __align__(16) __hip_bfloat16 ob[16];
#pragma unroll
  for (int i = 0; i < 16; ++i)
    ob[i] = __float2bfloat16(ga[i] * (va[i] - mu) * rs + be[i]);

  __hip_bfloat16* dst = Xn + ((size_t)g * MPG + r) * D_DIM + lane * 16;
  ((uint4*)dst)[0] = *(const uint4*)&ob[0];
  ((uint4*)dst)[1] = *(const uint4*)&ob[8];
}

// ---------------------------------------------------------------------------
// Kernels 3/4: bf16 MFMA GEMM, 256x256 tile, BK=64, 8 waves (2Mx4N).
// 4 phases per K-tile: {[vmcnt(4) @ph1,ph3]; s_barrier; ds_read subtile;
//  stage 1 plane of tile t+1; setprio(1); 16 MFMA; setprio(0)}.
// NO explicit lgkmcnt drain / sched_barrier: fragment->MFMA deps are
// register-visible, so the compiler emits counted lgkmcnt and MFMAs start
// while later reads drain (m97 asm evidence). gll FIFO order is preserved
// across barriers + "memory"-clobber vmcnt asm => counted vmcnt(4) retires
// exactly the 2 planes read next (issued 2-4 phases = >2000 cyc earlier).
//
// LDS 2x64KB buffers, 4 planes {A kh0, B kh0, A kh1, B kh1} @ 16KB each.
// Plane = [128 lines][128B], line = row-pair; 16B-slot permutation
//   phys_slot(r,s) = ((r&1)*4+s) ^ ((r>>1)&7)
// on read side + inverse on per-lane global source; LDS dest linear
// (rule 21). Conflict-free (R2/R3/R4: SQ_LDS_BANK_CONFLICT = 0).
// Final tile stages nothing -> buffer0 (lower 64KB) is free for the
// coalesced epilogue (per-wave private 4352B slices, no extra barrier:
// NT even => last tile reads buffer1 only).
// ---------------------------------------------------------------------------
template <bool SECOND>
__global__ __launch_bounds__(512, 2) void gemm_kernel(
    const __hip_bfloat16* __restrict__ A,
    const __hip_bfloat16* __restrict__ Bw,
    const float* __restrict__ bias,
    const float* __restrict__ xres,
    const int* __restrict__ idx,
    __hip_bfloat16* __restrict__ obf,
    float* __restrict__ of32,
    const int N, const int K, const int NT)
{
  extern __shared__ char lds[];     // 131072 bytes
  const int ntile = N >> 8;
  const int nwg = gridDim.x;
  const int bid0 = blockIdx.x;
  const int bid = (bid0 & 7) * (nwg >> 3) + (bid0 >> 3);   // XCD-contiguous
  const int mt = bid / ntile, nt = bid % ntile;
  const int g  = mt >> 4;
  const int tid = threadIdx.x;
  const int w = tid >> 6, lane = tid & 63;
  const int wm = w >> 2, wn = w & 3;

  const __hip_bfloat16* Ab = A + (size_t)mt * 256 * K;
  const __hip_bfloat16* Bb = Bw + ((size_t)g * N + (size_t)nt * 256) * K;

  // staging decode: inverse slot permutation on the global source address
  const int sp   = (lane & 7) ^ ((lane >> 3) & 7);
  const int srow = 2 * (lane >> 3) + (sp >> 2);
  const int skof = (sp & 3) * 8;
  const __hip_bfloat16* Ag0 = Ab + (size_t)(w * 32 + srow) * K + skof;
  const __hip_bfloat16* Ag1 = Ag0 + (size_t)16 * K;
  const __hip_bfloat16* Bg0 = Bb + (size_t)(w * 32 + srow) * K + skof;
  const __hip_bfloat16* Bg1 = Bg0 + (size_t)16 * K;

  // read-side lane constant (physical slot)
  const int l15 = lane & 15, sl = lane >> 4;
  const int slot_phys = (((l15 & 1) << 2) + sl) ^ ((l15 >> 1) & 7);
  const int lane_c = ((l15 >> 1) << 7) + (slot_phys << 4);

  f32x4 acc[8][4] = {};
  short8 frA[4], frB[4];

#define STAGE(BUFX, MAT, KH, TN) {                                          \
    const int koff = (TN) * 64 + (KH) * 32;                                 \
    char* d = lds + (BUFX) + ((KH) * 2 + (MAT)) * 16384 + w * 2048;         \
    if (MAT) { gll16(Bg0 + koff, d); gll16(Bg1 + koff, d + 1024); }         \
    else     { gll16(Ag0 + koff, d); gll16(Ag1 + koff, d + 1024); } }

#define RDA(BUFX, KH, MH) {                                                 \
    const char* base_ = lds + (BUFX) + (KH) * 32768 + wm * 8192 +           \
                        (MH) * 4096 + lane_c;                               \
    _Pragma("unroll") for (int mm = 0; mm < 4; ++mm)                        \
      frA[mm] = *(const short8*)(base_ + mm * 1024); }

#define RDB(BUFX, KH) {                                                     \
    const char* base_ = lds + (BUFX) + 16384 + (KH) * 32768 + wn * 4096 +   \
                        lane_c;                                             \
    _Pragma("unroll") for (int n = 0; n < 4; ++n)                           \
      frB[n] = *(const short8*)(base_ + n * 1024); }

#define MF(MH) {                                                            \
    __builtin_amdgcn_s_setprio(1);                                          \
    _Pragma("unroll") for (int mm = 0; mm < 4; ++mm)                        \
      _Pragma("unroll") for (int n = 0; n < 4; ++n)                         \
        acc[(MH) * 4 + mm][n] = __builtin_amdgcn_mfma_f32_16x16x32_bf16(    \
            frA[mm], frB[n], acc[(MH) * 4 + mm][n], 0, 0, 0);               \
    __builtin_amdgcn_s_setprio(0); }

  // prologue: stage all 4 planes of tile 0 into buffer 0
  STAGE(0, 0, 0, 0); STAGE(0, 1, 0, 0); STAGE(0, 0, 1, 0); STAGE(0, 1, 1, 0);

  for (int t = 0; t < NT; ++t) {
    const int bufb = (t & 1) << 16;
    const int bufx = bufb ^ 65536;
    const int more = (t + 1 < NT);
    const int tn = more ? t + 1 : 0;
    // ph1: vmcnt(4) retires A/B kh0 of tile t ; barrier publishes
    VMC4();
    BAR();
    RDB(bufb, 0); RDA(bufb, 0, 0);
    if (more) STAGE(bufx, 0, 0, tn);
    MF(0);
    // ph2
    BAR();
    RDA(bufb, 0, 1);
    if (more) STAGE(bufx, 1, 0, tn);
    MF(1);
    // ph3: vmcnt(4) retires A/B kh1 of tile t
    VMC4();
    BAR();
    RDB(bufb, 1); RDA(bufb, 1, 0);
    if (more) STAGE(bufx, 0, 1, tn);
    MF(0);
    // ph4
    BAR();
    RDA(bufb, 1, 1);
    if (more) STAGE(bufx, 1, 1, tn);
    MF(1);
  }
#undef STAGE
#undef RDA
#undef RDB
#undef MF

  // -------- coalesced epilogue (per-wave private LDS slice in buffer 0) ----
  // C/D layout: col = lane&15, row = (lane>>4)*4 + i   [m89/m91]
  const int cc  = lane & 15;
  const int cr4 = (lane >> 4) * 4;

  float bv[4];
#pragma unroll
  for (int n = 0; n < 4; ++n)
    bv[n] = bias[(size_t)g * N + nt * 256 + wn * 64 + n * 16 + cc];

  float* wsl = (float*)(lds + w * 4352);     // 16 rows x stride 68 f32
  const int rr  = lane >> 3;                 // 0..7
  const int c8  = (lane & 7) * 8;            // 0..56
  const int gcol0 = nt * 256 + wn * 64 + c8;

  if constexpr (!SECOND) {
    // H1 = relu(acc + bias) -> bf16, rows in group-gathered order
#pragma unroll
    for (int p = 0; p < 8; ++p) {            // p == m index (16 rows each)
      // scatter acc -> LDS (2-way free: verified bank math)
#pragma unroll
      for (int n = 0; n < 4; ++n)
#pragma unroll
        for (int i = 0; i < 4; ++i)
          wsl[(cr4 + i) * 68 + n * 16 + cc] = fmaxf(acc[p][n][i] + bv[n], 0.0f);
      const int grow0 = mt * 256 + wm * 128 + p * 16;
#pragma unroll
      for (int it = 0; it < 2; ++it) {
        const int r = it * 8 + rr;
        float4 v0 = *(const float4*)&wsl[r * 68 + c8];
        float4 v1 = *(const float4*)&wsl[r * 68 + c8 + 4];
        __align__(16) __hip_bfloat16 ob[8];
        ob[0] = __float2bfloat16(v0.x); ob[1] = __float2bfloat16(v0.y);
        ob[2] = __float2bfloat16(v0.z); ob[3] = __float2bfloat16(v0.w);
        ob[4] = __float2bfloat16(v1.x); ob[5] = __float2bfloat16(v1.y);
        ob[6] = __float2bfloat16(v1.z); ob[7] = __float2bfloat16(v1.w);
        *(uint4*)&obf[(size_t)(grow0 + r) * N + gcol0] = *(const uint4*)ob;
      }
    }
  } else {
    // out = acc + bias + xres, scattered to original batch rows (f32)
    const int rbase = (mt & 15) * 256;
    const int b = idx[g * 8 + (rbase >> 9)];
    const size_t ob = (size_t)b * S_DIM * D_DIM;
#pragma unroll
    for (int p = 0; p < 8; ++p) {
#pragma unroll
      for (int n = 0; n < 4; ++n)
#pragma unroll
        for (int i = 0; i < 4; ++i)
          wsl[(cr4 + i) * 68 + n * 16 + cc] = acc[p][n][i] + bv[n];
      const int rloc0 = rbase + wm * 128 + p * 16;
#pragma unroll
      for (int it = 0; it < 2; ++it) {
        const int r = it * 8 + rr;
        const int tok = (rloc0 + r) & 511;
        const size_t off = ob + (size_t)tok * D_DIM + gcol0;
        float4 v0 = *(const float4*)&wsl[r * 68 + c8];
        float4 v1 = *(const float4*)&wsl[r * 68 + c8 + 4];
        float4 x0 = *(const float4*)&xres[off];
        float4 x1 = *(const float4*)&xres[off + 4];
        v0.x += x0.x; v0.y += x0.y; v0.z += x0.z; v0.w += x0.w;
        v1.x += x1.x; v1.y += x1.y; v1.z += x1.z; v1.w += x1.w;
        *(float4*)&of32[off]     = v0;
        *(float4*)&of32[off + 4] = v1;
      }
    }
  }
}

// ---------------------------------------------------------------------------
extern "C" void kernel_launch(void* const* d_in, const int* in_sizes, int n_in,
                              void* d_out, int out_size, void* d_ws, size_t ws_size,
                              hipStream_t stream) {
  const float* x  = (const float*)d_in[0];
  const int*   idx = (const int*)d_in[1];
  const float* W1 = (const float*)d_in[2];
  const float* B1 = (const float*)d_in[3];
  const float* W2 = (const float*)d_in[4];
  const float* B2 = (const float*)d_in[5];
  const float* G  = (const float*)d_in[6];
  const float* Bn = (const float*)d_in[7];
  float* out = (float*)d_out;

  char* ws = (char*)d_ws;
  __hip_bfloat16* Xn  = (__hip_bfloat16*)(ws);                    // 32 MiB
  __hip_bfloat16* W1t = (__hip_bfloat16*)(ws + 33554432);         // 16 MiB
  __hip_bfloat16* W2t = (__hip_bfloat16*)(ws + 50331648);         // 16 MiB
  __hip_bfloat16* H1  = (__hip_bfloat16*)(ws + 67108864);         // 64 MiB

  (void)hipFuncSetAttribute((const void*)gemm_kernel<false>,
                            hipFuncAttributeMaxDynamicSharedMemorySize, 131072);
  (void)hipFuncSetAttribute((const void*)gemm_kernel<true>,
                            hipFuncAttributeMaxDynamicSharedMemorySize, 131072);

  transpose_cast_kernel<<<dim3(16384), dim3(256), 0, stream>>>(W1, W2, W1t, W2t);
  ln_gather_kernel<<<dim3(4096), dim3(256), 0, stream>>>(x, idx, G, Bn, Xn);
  gemm_kernel<false><<<dim3(512), dim3(512), 131072, stream>>>(
      Xn, W1t, B1, nullptr, nullptr, H1, nullptr, F_DIM, D_DIM, 16);
  gemm_kernel<true><<<dim3(256), dim3(512), 131072, stream>>>(
      H1, W2t, B2, x, idx, nullptr, out, D_DIM, F_DIM, 32);
}

// Round 6
// 171.178 us; speedup vs baseline: 1.1544x; 1.0741x over previous
//
#include <hip/hip_runtime.h>
#include <hip/hip_bf16.h>

// StackedAdapter: out[b] = x[b] + W2[g]^T·relu(W1[g]^T·LN(x[b]) + B1[g]) + B2[g]
// B=32, S=512, D=1024, F=2048. 16384 tokens, 4096 per group, 4 groups.

#define S_DIM 512
#define D_DIM 1024
#define F_DIM 2048
#define MPG   4096

typedef __attribute__((ext_vector_type(8))) short  short8;   // 8 bf16
typedef __attribute__((ext_vector_type(4))) float  f32x4;

__device__ __forceinline__ void gll16(const void* g, void* l) {
  __builtin_amdgcn_global_load_lds((__attribute__((address_space(1))) void*)g,
                                   (__attribute__((address_space(3))) void*)l,
                                   16, 0, 0);
}
#define VMC0()  asm volatile("s_waitcnt vmcnt(0)" ::: "memory")
#define SB()    __builtin_amdgcn_sched_barrier(0)
#define BAR()   __builtin_amdgcn_s_barrier()

// ---------------------------------------------------------------------------
// Kernel 1 (merged): weight transpose-cast  +  LayerNorm/gather.
//   blocks [0, 16384)    : W1/W2 [g][K][N] f32 -> [g][N][K] bf16 (32x32 tiles)
//   blocks [16384, 20480): LN + gather into group-major bf16 Xn
// ---------------------------------------------------------------------------
__global__ __launch_bounds__(256) void prep_kernel(
    const float* __restrict__ W1, const float* __restrict__ W2,
    const float* __restrict__ x,  const int* __restrict__ idx,
    const float* __restrict__ G,  const float* __restrict__ Bn,
    __hip_bfloat16* __restrict__ W1t, __hip_bfloat16* __restrict__ W2t,
    __hip_bfloat16* __restrict__ Xn)
{
  __shared__ float tl[32][33];
  const int bid = blockIdx.x;
  if (bid < 16384) {
    const float* src; __hip_bfloat16* dst;
    int R, C, tr, tc;
    if (bid < 8192) {                 // W1: [4][1024][2048] -> [4][2048][1024]
      const int g = bid >> 11, t = bid & 2047;
      R = 1024; C = 2048; tr = t >> 6; tc = t & 63;
      src = W1 + (size_t)g * R * C;
      dst = W1t + (size_t)g * R * C;
    } else {                          // W2: [4][2048][1024] -> [4][1024][2048]
      const int b2 = bid - 8192;
      const int g = b2 >> 11, t = b2 & 2047;
      R = 2048; C = 1024; tr = t >> 5; tc = t & 31;
      src = W2 + (size_t)g * R * C;
      dst = W2t + (size_t)g * R * C;
    }
    const int tx = threadIdx.x & 31, ty = threadIdx.x >> 5;
    const int r0 = tr * 32, c0 = tc * 32;
#pragma unroll
    for (int i = 0; i < 4; ++i)
      tl[ty + 8 * i][tx] = src[(size_t)(r0 + ty + 8 * i) * C + (c0 + tx)];
    __syncthreads();
#pragma unroll
    for (int i = 0; i < 4; ++i)
      dst[(size_t)(c0 + ty + 8 * i) * R + (r0 + tx)] = __float2bfloat16(tl[tx][ty + 8 * i]);
    return;
  }
  // ---- LayerNorm + gather ----
  const int lb   = bid - 16384;
  const int wid  = lb * 4 + (threadIdx.x >> 6);
  const int lane = threadIdx.x & 63;
  const int g = wid >> 12;
  const int r = wid & 4095;
  const int j = r >> 9;
  const int tok = r & 511;
  const int b = idx[g * 8 + j];

  const float* src = x + ((size_t)b * S_DIM + tok) * D_DIM + lane * 16;
  float4 vq[4];
#pragma unroll
  for (int i = 0; i < 4; ++i) vq[i] = ((const float4*)src)[i];
  const float* va = (const float*)vq;

  float s = 0.f, s2 = 0.f;
#pragma unroll
  for (int i = 0; i < 16; ++i) { s += va[i]; s2 += va[i] * va[i]; }
#pragma unroll
  for (int o = 32; o > 0; o >>= 1) { s += __shfl_xor(s, o); s2 += __shfl_xor(s2, o); }

  const float mu  = s * (1.0f / 1024.0f);
  float var = fmaxf(s2 * (1.0f / 1024.0f) - mu * mu, 0.0f) * (1024.0f / 1023.0f);
  const float rs  = 1.0f / (sqrtf(var) + 1e-6f);

  float4 gq[4], bq[4];
  const float* gp = G  + (size_t)g * D_DIM + lane * 16;
  const float* bp = Bn + (size_t)g * D_DIM + lane * 16;
#pragma unroll
  for (int i = 0; i < 4; ++i) { gq[i] = ((const float4*)gp)[i]; bq[i] = ((const float4*)bp)[i]; }
  const float* ga = (const float*)gq;
  const float* be = (const float*)bq;

  __align__(16) __hip_bfloat16 ob[16];
#pragma unroll
  for (int i = 0; i < 16; ++i)
    ob[i] = __float2bfloat16(ga[i] * (va[i] - mu) * rs + be[i]);

  __hip_bfloat16* dst = Xn + ((size_t)g * MPG + r) * D_DIM + lane * 16;
  ((uint4*)dst)[0] = *(const uint4*)&ob[0];
  ((uint4*)dst)[1] = *(const uint4*)&ob[8];
}

// ---------------------------------------------------------------------------
// Kernels 2/3: bf16 MFMA GEMM, 256x256 tile, BK=64, 8 waves (2Mx4N).
// TWO phases per K-tile, ONE barrier + ONE vmcnt per K-tile:
//   ph1: vmcnt(0) [tile t's 8 glls, issued 1 K-tile earlier => covered];
//        s_barrier; sched_barrier; read B frags (both kh, held in regs) +
//        A frags MH0; 32-MFMA cluster (MH0).
//   ph2: stage ALL 4 planes of tile t+1 into the other buffer (8 gll);
//        read A frags MH1; 32-MFMA cluster (MH1).   [no sync at all]
// Publish rule: own-vmcnt BEFORE the barrier (each wave drains its glls,
// then the barrier makes all waves' planes visible). Staging bufx at ph2(t)
// races nothing: bufx's previous readers (tile t-1) finished before this
// tile's barrier. ds ops cannot hoist above the barrier (SB) or sink across
// the memory-clobber vmcnt asm.
//
// LDS 2x64KB buffers, 4 planes {A kh0, B kh0, A kh1, B kh1} @ 16KB each.
// Plane = [128 lines][128B], line = row-pair; 16B-slot permutation
//   phys_slot(r,s) = ((r&1)*4+s) ^ ((r>>1)&7)
// on read side + inverse on per-lane global source; LDS dest linear
// (rule 21). Conflict-free (R2-R5: SQ_LDS_BANK_CONFLICT ~ 0).
// NT odd => last tile reads buffer1, buffer0 free for coalesced epilogue.
// ---------------------------------------------------------------------------
template <bool SECOND>
__global__ __launch_bounds__(512, 2) void gemm_kernel(
    const __hip_bfloat16* __restrict__ A,
    const __hip_bfloat16* __restrict__ Bw,
    const float* __restrict__ bias,
    const float* __restrict__ xres,
    const int* __restrict__ idx,
    __hip_bfloat16* __restrict__ obf,
    float* __restrict__ of32,
    const int N, const int K, const int NT)
{
  extern __shared__ char lds[];     // 131072 bytes
  const int ntile = N >> 8;
  const int nwg = gridDim.x;
  const int bid0 = blockIdx.x;
  const int bid = (bid0 & 7) * (nwg >> 3) + (bid0 >> 3);   // XCD-contiguous
  const int mt = bid / ntile, nt = bid % ntile;
  const int g  = mt >> 4;
  const int tid = threadIdx.x;
  const int w = tid >> 6, lane = tid & 63;
  const int wm = w >> 2, wn = w & 3;

  const __hip_bfloat16* Ab = A + (size_t)mt * 256 * K;
  const __hip_bfloat16* Bb = Bw + ((size_t)g * N + (size_t)nt * 256) * K;

  // staging decode: inverse slot permutation on the global source address
  const int sp   = (lane & 7) ^ ((lane >> 3) & 7);
  const int srow = 2 * (lane >> 3) + (sp >> 2);
  const int skof = (sp & 3) * 8;
  const __hip_bfloat16* Ag0 = Ab + (size_t)(w * 32 + srow) * K + skof;
  const __hip_bfloat16* Ag1 = Ag0 + (size_t)16 * K;
  const __hip_bfloat16* Bg0 = Bb + (size_t)(w * 32 + srow) * K + skof;
  const __hip_bfloat16* Bg1 = Bg0 + (size_t)16 * K;

  // read-side lane constant (physical slot)
  const int l15 = lane & 15, sl = lane >> 4;
  const int slot_phys = (((l15 & 1) << 2) + sl) ^ ((l15 >> 1) & 7);
  const int lane_c = ((l15 >> 1) << 7) + (slot_phys << 4);

  f32x4 acc[8][4] = {};
  short8 frA[2][4], frB[2][4];

  // stage all 4 planes (A kh0, B kh0, A kh1, B kh1) of K-tile TN into BUFX
#define STAGE4(BUFX, TN) {                                                  \
    const int k0 = (TN) * 64;                                               \
    char* d0 = lds + (BUFX) + w * 2048;                                     \
    gll16(Ag0 + k0,      d0);         gll16(Ag1 + k0,      d0 + 1024);      \
    gll16(Bg0 + k0,      d0 + 16384); gll16(Bg1 + k0,      d0 + 17408);     \
    gll16(Ag0 + k0 + 32, d0 + 32768); gll16(Ag1 + k0 + 32, d0 + 33792);     \
    gll16(Bg0 + k0 + 32, d0 + 49152); gll16(Bg1 + k0 + 32, d0 + 50176); }

#define RDA2(BUFB, MH) {                                                    \
    _Pragma("unroll") for (int kh = 0; kh < 2; ++kh) {                      \
      const char* b_ = lds + (BUFB) + kh * 32768 + wm * 8192 +              \
                       (MH) * 4096 + lane_c;                                \
      _Pragma("unroll") for (int mm = 0; mm < 4; ++mm)                      \
        frA[kh][mm] = *(const short8*)(b_ + mm * 1024); } }

#define RDB2(BUFB) {                                                        \
    _Pragma("unroll") for (int kh = 0; kh < 2; ++kh) {                      \
      const char* b_ = lds + (BUFB) + 16384 + kh * 32768 + wn * 4096 +      \
                       lane_c;                                              \
      _Pragma("unroll") for (int n = 0; n < 4; ++n)                         \
        frB[kh][n] = *(const short8*)(b_ + n * 1024); } }

#define MF32(MH) {                                                          \
    __builtin_amdgcn_s_setprio(1);                                          \
    _Pragma("unroll") for (int kh = 0; kh < 2; ++kh)                        \
      _Pragma("unroll") for (int mm = 0; mm < 4; ++mm)                      \
        _Pragma("unroll") for (int n = 0; n < 4; ++n)                       \
          acc[(MH) * 4 + mm][n] = __builtin_amdgcn_mfma_f32_16x16x32_bf16(  \
              frA[kh][mm], frB[kh][n], acc[(MH) * 4 + mm][n], 0, 0, 0);     \
    __builtin_amdgcn_s_setprio(0); }

  // prologue: stage tile 0 into buffer 0
  STAGE4(0, 0);

  for (int t = 0; t < NT; ++t) {
    const int bufb = (t & 1) << 16;
    const int bufx = bufb ^ 65536;
    // ph1: drain own glls, rendezvous, consume MH0 over full K=64
    VMC0();
    BAR();
    SB();
    RDB2(bufb);
    RDA2(bufb, 0);
    MF32(0);
    // ph2: prefetch tile t+1 (no sync), consume MH1
    if (t + 1 < NT) STAGE4(bufx, t + 1);
    RDA2(bufb, 1);
    MF32(1);
  }
#undef STAGE4
#undef RDA2
#undef RDB2
#undef MF32

  // -------- coalesced epilogue (per-wave private LDS slice in buffer 0) ----
  // C/D layout: col = lane&15, row = (lane>>4)*4 + i   [m89/m91]
  const int cc  = lane & 15;
  const int cr4 = (lane >> 4) * 4;

  float bv[4];
#pragma unroll
  for (int n = 0; n < 4; ++n)
    bv[n] = bias[(size_t)g * N + nt * 256 + wn * 64 + n * 16 + cc];

  float* wsl = (float*)(lds + w * 4352);     // 16 rows x stride 68 f32
  const int rr  = lane >> 3;                 // 0..7
  const int c8  = (lane & 7) * 8;            // 0..56
  const int gcol0 = nt * 256 + wn * 64 + c8;

  if constexpr (!SECOND) {
    // H1 = relu(acc + bias) -> bf16, rows in group-gathered order
#pragma unroll
    for (int p = 0; p < 8; ++p) {
#pragma unroll
      for (int n = 0; n < 4; ++n)
#pragma unroll
        for (int i = 0; i < 4; ++i)
          wsl[(cr4 + i) * 68 + n * 16 + cc] = fmaxf(acc[p][n][i] + bv[n], 0.0f);
      const int grow0 = mt * 256 + wm * 128 + p * 16;
#pragma unroll
      for (int it = 0; it < 2; ++it) {
        const int r = it * 8 + rr;
        float4 v0 = *(const float4*)&wsl[r * 68 + c8];
        float4 v1 = *(const float4*)&wsl[r * 68 + c8 + 4];
        __align__(16) __hip_bfloat16 ob[8];
        ob[0] = __float2bfloat16(v0.x); ob[1] = __float2bfloat16(v0.y);
        ob[2] = __float2bfloat16(v0.z); ob[3] = __float2bfloat16(v0.w);
        ob[4] = __float2bfloat16(v1.x); ob[5] = __float2bfloat16(v1.y);
        ob[6] = __float2bfloat16(v1.z); ob[7] = __float2bfloat16(v1.w);
        *(uint4*)&obf[(size_t)(grow0 + r) * N + gcol0] = *(const uint4*)ob;
      }
    }
  } else {
    // out = acc + bias + xres, scattered to original batch rows (f32)
    const int rbase = (mt & 15) * 256;
    const int b = idx[g * 8 + (rbase >> 9)];
    const size_t ob = (size_t)b * S_DIM * D_DIM;
#pragma unroll
    for (int p = 0; p < 8; ++p) {
#pragma unroll
      for (int n = 0; n < 4; ++n)
#pragma unroll
        for (int i = 0; i < 4; ++i)
          wsl[(cr4 + i) * 68 + n * 16 + cc] = acc[p][n][i] + bv[n];
      const int rloc0 = rbase + wm * 128 + p * 16;
#pragma unroll
      for (int it = 0; it < 2; ++it) {
        const int r = it * 8 + rr;
        const int tok = (rloc0 + r) & 511;
        const size_t off = ob + (size_t)tok * D_DIM + gcol0;
        float4 v0 = *(const float4*)&wsl[r * 68 + c8];
        float4 v1 = *(const float4*)&wsl[r * 68 + c8 + 4];
        float4 x0 = *(const float4*)&xres[off];
        float4 x1 = *(const float4*)&xres[off + 4];
        v0.x += x0.x; v0.y += x0.y; v0.z += x0.z; v0.w += x0.w;
        v1.x += x1.x; v1.y += x1.y; v1.z += x1.z; v1.w += x1.w;
        *(float4*)&of32[off]     = v0;
        *(float4*)&of32[off + 4] = v1;
      }
    }
  }
}

// ---------------------------------------------------------------------------
extern "C" void kernel_launch(void* const* d_in, const int* in_sizes, int n_in,
                              void* d_out, int out_size, void* d_ws, size_t ws_size,
                              hipStream_t stream) {
  const float* x  = (const float*)d_in[0];
  const int*   idx = (const int*)d_in[1];
  const float* W1 = (const float*)d_in[2];
  const float* B1 = (const float*)d_in[3];
  const float* W2 = (const float*)d_in[4];
  const float* B2 = (const float*)d_in[5];
  const float* G  = (const float*)d_in[6];
  const float* Bn = (const float*)d_in[7];
  float* out = (float*)d_out;

  char* ws = (char*)d_ws;
  __hip_bfloat16* Xn  = (__hip_bfloat16*)(ws);                    // 32 MiB
  __hip_bfloat16* W1t = (__hip_bfloat16*)(ws + 33554432);         // 16 MiB
  __hip_bfloat16* W2t = (__hip_bfloat16*)(ws + 50331648);         // 16 MiB
  __hip_bfloat16* H1  = (__hip_bfloat16*)(ws + 67108864);         // 64 MiB

  (void)hipFuncSetAttribute((const void*)gemm_kernel<false>,
                            hipFuncAttributeMaxDynamicSharedMemorySize, 131072);
  (void)hipFuncSetAttribute((const void*)gemm_kernel<true>,
                            hipFuncAttributeMaxDynamicSharedMemorySize, 131072);

  prep_kernel<<<dim3(20480), dim3(256), 0, stream>>>(
      W1, W2, x, idx, G, Bn, W1t, W2t, Xn);
  gemm_kernel<false><<<dim3(512), dim3(512), 131072, stream>>>(
      Xn, W1t, B1, nullptr, nullptr, H1, nullptr, F_DIM, D_DIM, 16);
  gemm_kernel<true><<<dim3(256), dim3(512), 131072, stream>>>(
      H1, W2t, B2, x, idx, nullptr, out, D_DIM, F_DIM, 32);
}